// Round 1
// 69.603 us; speedup vs baseline: 1.0369x; 1.0369x over previous
//
#include <hip/hip_runtime.h>
#include <math.h>

#define NQ 4
#define NL 6
#define DIM 16
#define BLOCK 256

// One thread = one batch sample. State (16 complex amps) lives in registers.
// Rot matrices are batch-uniform: threads 0..23 of each block build them in
// LDS once (broadcast reads thereafter -> no bank conflicts).
//
// R1 change: the 6 entangling layers are NO LONGER fully unrolled. They run
// as a `#pragma unroll 1` loop over 2 macro-iterations of 3 layers each
// (r = l%3+1 = 1,2,3 is compile-time inside the macro body, so all state
// register indices stay static and CNOTs remain register renames). This
// halves the instruction footprint (~30 KB -> ~15 KB) so the stream fits
// L1I: at only 2 waves/SIMD the fully-unrolled version was instruction-
// fetch-latency bound (VALUBusy 25% with no memory or dependency limiter).
__global__ __launch_bounds__(BLOCK) void vqc_kernel(
    const float* __restrict__ inputs,   // [B, 4]
    const float* __restrict__ rot,      // [6, 4, 3]
    float* __restrict__ out,            // [B, 4]
    int batch)
{
    __shared__ float U[NL * NQ][8];  // u00r,u00i,u01r,u01i,u10r,u10i,u11r,u11i

    const int tid = threadIdx.x;
    if (tid < NL * NQ) {
        float phi = rot[tid * 3 + 0];
        float theta = rot[tid * 3 + 1];
        float omega = rot[tid * 3 + 2];
        float st, ct;
        __sincosf(0.5f * theta, &st, &ct);
        float a = 0.5f * (phi + omega);   // ep = exp(-i a) = ca - i sa
        float b = 0.5f * (phi - omega);   // em = exp(+i b) = cb + i sb
        float sa, ca, sb, cb;
        __sincosf(a, &sa, &ca);
        __sincosf(b, &sb, &cb);
        U[tid][0] = ca * ct;   // u00 = ep*ct
        U[tid][1] = -sa * ct;
        U[tid][2] = -cb * st;  // u01 = -em*st
        U[tid][3] = -sb * st;
        U[tid][4] = cb * st;   // u10 = conj(em)*st
        U[tid][5] = -sb * st;
        U[tid][6] = ca * ct;   // u11 = conj(ep)*ct
        U[tid][7] = sa * ct;
    }
    __syncthreads();

    const int b = blockIdx.x * BLOCK + tid;
    if (b >= batch) return;

    // ---- AngleEmbedding: product state directly ----
    const float4 x = ((const float4*)inputs)[b];
    float c[NQ], s[NQ];
    __sincosf(0.5f * x.x, &s[0], &c[0]);
    __sincosf(0.5f * x.y, &s[1], &c[1]);
    __sincosf(0.5f * x.z, &s[2], &c[2]);
    __sincosf(0.5f * x.w, &s[3], &c[3]);

    float sr[DIM], si[DIM];
#pragma unroll
    for (int i = 0; i < DIM; ++i) {
        // qubit q <-> bit (3-q) of i
        float mag = (((i >> 3) & 1) ? s[0] : c[0])
                  * (((i >> 2) & 1) ? s[1] : c[1])
                  * (((i >> 1) & 1) ? s[2] : c[2])
                  * (((i >> 0) & 1) ? s[3] : c[3]);
        const int k = (((i >> 3) & 1) + ((i >> 2) & 1) + ((i >> 1) & 1) + (i & 1)) & 3;
        // (-i)^k: 0->(1,0) 1->(0,-1) 2->(-1,0) 3->(0,1)
        sr[i] = (k == 0) ? mag : ((k == 2) ? -mag : 0.0f);
        si[i] = (k == 1) ? -mag : ((k == 3) ? mag : 0.0f);
    }

    // ---- StronglyEntanglingLayers: 2 macro-iterations x 3 layers ----
    // l = half*3 + li, so l % 3 == li and r = li + 1 is compile-time.
#pragma unroll 1
    for (int half = 0; half < 2; ++half) {
        const int ubase = half * (3 * NQ);
#pragma unroll
        for (int li = 0; li < 3; ++li) {
#pragma unroll
            for (int q = 0; q < NQ; ++q) {
                const float* u = U[ubase + li * NQ + q];
                const float u00r = u[0], u00i = u[1], u01r = u[2], u01i = u[3];
                const float u10r = u[4], u10i = u[5], u11r = u[6], u11i = u[7];
                const int m = 1 << (3 - q);
#pragma unroll
                for (int i = 0; i < DIM; ++i) {
                    if (!(i & m)) {
                        const int j = i | m;
                        const float a0r = sr[i], a0i = si[i];
                        const float a1r = sr[j], a1i = si[j];
                        sr[i] = u00r * a0r - u00i * a0i + u01r * a1r - u01i * a1i;
                        si[i] = u00r * a0i + u00i * a0r + u01r * a1i + u01i * a1r;
                        sr[j] = u10r * a0r - u10i * a0i + u11r * a1r - u11i * a1i;
                        si[j] = u10r * a0i + u10i * a0r + u11r * a1i + u11i * a1r;
                    }
                }
            }
            const int r = li + 1;  // compile-time within the unrolled macro body
#pragma unroll
            for (int q = 0; q < NQ; ++q) {
                const int t = (q + r) & 3;
                const int cm = 1 << (3 - q);
                const int tm = 1 << (3 - t);
#pragma unroll
                for (int i = 0; i < DIM; ++i) {
                    if ((i & cm) && !(i & tm)) {
                        const int j = i | tm;
                        float tr = sr[i]; sr[i] = sr[j]; sr[j] = tr;
                        float ti = si[i]; si[i] = si[j]; si[j] = ti;
                    }
                }
            }
        }
    }

    // ---- <Z_q> from probabilities ----
    float e0 = 0.f, e1 = 0.f, e2 = 0.f, e3 = 0.f;
#pragma unroll
    for (int i = 0; i < DIM; ++i) {
        const float p = sr[i] * sr[i] + si[i] * si[i];
        e0 += ((i >> 3) & 1) ? -p : p;
        e1 += ((i >> 2) & 1) ? -p : p;
        e2 += ((i >> 1) & 1) ? -p : p;
        e3 += ((i >> 0) & 1) ? -p : p;
    }
    ((float4*)out)[b] = make_float4(e0, e1, e2, e3);
}

extern "C" void kernel_launch(void* const* d_in, const int* in_sizes, int n_in,
                              void* d_out, int out_size, void* d_ws, size_t ws_size,
                              hipStream_t stream) {
    const float* inputs = (const float*)d_in[0];   // [B,4] fp32
    const float* rot = (const float*)d_in[1];      // [6,4,3] fp32
    float* out = (float*)d_out;                    // [B,4] fp32
    const int batch = in_sizes[0] / NQ;
    const int grid = (batch + BLOCK - 1) / BLOCK;
    vqc_kernel<<<grid, BLOCK, 0, stream>>>(inputs, rot, out, batch);
}

// Round 3
// 63.563 us; speedup vs baseline: 1.1354x; 1.0950x over previous
//
#include <hip/hip_runtime.h>
#include <math.h>

#define NQ 4
#define NL 6
#define DIM 16
#define NV 8      // 8 float2 regs hold 16 amplitudes: vec k = (amp[2k], amp[2k+1])
#define BLOCK 256

typedef float v2 __attribute__((ext_vector_type(2)));

// One thread = one batch sample. State: 16 complex amps packed as 8 float2
// (re) + 8 float2 (im); basis index i = 2k + slot. All gate updates are
// SIMD-2 across the two slots -> v_pk_fma_f32 (VOP3P packed fp32), halving
// issued VALU instructions AND code footprint vs the scalar version.
// Qubit q <-> bit (3-q) of i; qubits 0..2 live in the register index k
// (bit 2-q), qubit 3 is the slot bit.
//
// R1: 6 layers rolled as 2 macro-iterations x 3 layers (I-cache fit).
// R2: packed fp32 state. R3: resubmit of R2 (infra container failure).
__global__ __launch_bounds__(BLOCK) void vqc_kernel(
    const float* __restrict__ inputs,   // [B, 4]
    const float* __restrict__ rot,      // [6, 4, 3]
    float* __restrict__ out,            // [B, 4]
    int batch)
{
    __shared__ float U[NL * NQ][8];  // u00r,u00i,u01r,u01i,u10r,u10i,u11r,u11i

    const int tid = threadIdx.x;
    if (tid < NL * NQ) {
        float phi = rot[tid * 3 + 0];
        float theta = rot[tid * 3 + 1];
        float omega = rot[tid * 3 + 2];
        float st, ct;
        __sincosf(0.5f * theta, &st, &ct);
        float a = 0.5f * (phi + omega);   // ep = exp(-i a) = ca - i sa
        float b = 0.5f * (phi - omega);   // em = exp(+i b) = cb + i sb
        float sa, ca, sb, cb;
        __sincosf(a, &sa, &ca);
        __sincosf(b, &sb, &cb);
        U[tid][0] = ca * ct;   // u00 = ep*ct
        U[tid][1] = -sa * ct;
        U[tid][2] = -cb * st;  // u01 = -em*st
        U[tid][3] = -sb * st;
        U[tid][4] = cb * st;   // u10 = conj(em)*st
        U[tid][5] = -sb * st;
        U[tid][6] = ca * ct;   // u11 = conj(ep)*ct
        U[tid][7] = sa * ct;
    }
    __syncthreads();

    const int b = blockIdx.x * BLOCK + tid;
    if (b >= batch) return;

    // ---- AngleEmbedding: product state directly ----
    const float4 x = ((const float4*)inputs)[b];
    float c[NQ], s[NQ];
    __sincosf(0.5f * x.x, &s[0], &c[0]);
    __sincosf(0.5f * x.y, &s[1], &c[1]);
    __sincosf(0.5f * x.z, &s[2], &c[2]);
    __sincosf(0.5f * x.w, &s[3], &c[3]);

    float vr[DIM], vi[DIM];
#pragma unroll
    for (int i = 0; i < DIM; ++i) {
        float mag = (((i >> 3) & 1) ? s[0] : c[0])
                  * (((i >> 2) & 1) ? s[1] : c[1])
                  * (((i >> 1) & 1) ? s[2] : c[2])
                  * (((i >> 0) & 1) ? s[3] : c[3]);
        const int k = (((i >> 3) & 1) + ((i >> 2) & 1) + ((i >> 1) & 1) + (i & 1)) & 3;
        // (-i)^k: 0->(1,0) 1->(0,-1) 2->(-1,0) 3->(0,1)
        vr[i] = (k == 0) ? mag : ((k == 2) ? -mag : 0.0f);
        vi[i] = (k == 1) ? -mag : ((k == 3) ? mag : 0.0f);
    }
    v2 sr2[NV], si2[NV];
#pragma unroll
    for (int k = 0; k < NV; ++k) {
        sr2[k] = (v2){vr[2 * k], vr[2 * k + 1]};
        si2[k] = (v2){vi[2 * k], vi[2 * k + 1]};
    }

    // ---- StronglyEntanglingLayers: 2 macro-iterations x 3 layers ----
    // l = half*3 + li, so l % 3 == li and r = li + 1 is compile-time.
#pragma unroll 1
    for (int half = 0; half < 2; ++half) {
        const int ubase = half * (3 * NQ);
#pragma unroll
        for (int li = 0; li < 3; ++li) {
#pragma unroll
            for (int q = 0; q < NQ; ++q) {
                const float* u = U[ubase + li * NQ + q];
                const float u00r = u[0], u00i = u[1], u01r = u[2], u01i = u[3];
                const float u10r = u[4], u10i = u[5], u11r = u[6], u11i = u[7];
                if (q < 3) {
                    // pair partner is another whole register
                    const int m = 1 << (2 - q);
#pragma unroll
                    for (int k = 0; k < NV; ++k) {
                        if (!(k & m)) {
                            const int k2 = k | m;
                            const v2 a0r = sr2[k], a0i = si2[k];
                            const v2 a1r = sr2[k2], a1i = si2[k2];
                            sr2[k]  = u00r * a0r - u00i * a0i + u01r * a1r - u01i * a1i;
                            si2[k]  = u00r * a0i + u00i * a0r + u01r * a1i + u01i * a1r;
                            sr2[k2] = u10r * a0r - u10i * a0i + u11r * a1r - u11i * a1i;
                            si2[k2] = u10r * a0i + u10i * a0r + u11r * a1i + u11i * a1r;
                        }
                    }
                } else {
                    // qubit 3 = slot bit: partner is the other slot.
                    // slot0 out: u00*x0 + u01*x1 ; slot1 out: u11*x1 + u10*x0
                    const v2 dr = {u00r, u11r}, di = {u00i, u11i};
                    const v2 er = {u01r, u10r}, ei = {u01i, u10i};
#pragma unroll
                    for (int k = 0; k < NV; ++k) {
                        const v2 xr = sr2[k], xi = si2[k];
                        const v2 yr = __builtin_shufflevector(xr, xr, 1, 0);
                        const v2 yi = __builtin_shufflevector(xi, xi, 1, 0);
                        sr2[k] = dr * xr - di * xi + er * yr - ei * yi;
                        si2[k] = dr * xi + di * xr + er * yi + ei * yr;
                    }
                }
            }
            const int r = li + 1;  // compile-time within the unrolled macro body
#pragma unroll
            for (int q = 0; q < NQ; ++q) {
                const int t = (q + r) & 3;
                if (t == 3) {
                    // target = slot bit; control is reg bit (2-q): swap slots
                    const int cm = 1 << (2 - q);
#pragma unroll
                    for (int k = 0; k < NV; ++k) {
                        if (k & cm) {
                            sr2[k] = __builtin_shufflevector(sr2[k], sr2[k], 1, 0);
                            si2[k] = __builtin_shufflevector(si2[k], si2[k], 1, 0);
                        }
                    }
                } else if (q == 3) {
                    // control = slot bit: swap target bit for slot-1 amps only
                    const int tm = 1 << (2 - t);
#pragma unroll
                    for (int k = 0; k < NV; ++k) {
                        if (!(k & tm)) {
                            const int k2 = k | tm;
                            const v2 Ar = sr2[k], Br = sr2[k2];
                            const v2 Ai = si2[k], Bi = si2[k2];
                            sr2[k]  = __builtin_shufflevector(Ar, Br, 0, 3);
                            sr2[k2] = __builtin_shufflevector(Br, Ar, 0, 3);
                            si2[k]  = __builtin_shufflevector(Ai, Bi, 0, 3);
                            si2[k2] = __builtin_shufflevector(Bi, Ai, 0, 3);
                        }
                    }
                } else {
                    // pure register rename
                    const int cm = 1 << (2 - q);
                    const int tm = 1 << (2 - t);
#pragma unroll
                    for (int k = 0; k < NV; ++k) {
                        if ((k & cm) && !(k & tm)) {
                            const int k2 = k | tm;
                            v2 tr = sr2[k]; sr2[k] = sr2[k2]; sr2[k2] = tr;
                            v2 ti = si2[k]; si2[k] = si2[k2]; si2[k2] = ti;
                        }
                    }
                }
            }
        }
    }

    // ---- <Z_q> from probabilities ----
    // q=0..2 signs are slot-uniform (bit 2-q of k); q=3 sign differs per slot.
    v2 acc0 = {0.f, 0.f}, acc1 = {0.f, 0.f}, acc2 = {0.f, 0.f}, acc3 = {0.f, 0.f};
    const v2 sgn3 = {1.f, -1.f};
#pragma unroll
    for (int k = 0; k < NV; ++k) {
        const v2 p = sr2[k] * sr2[k] + si2[k] * si2[k];
        acc0 += ((k >> 2) & 1) ? -p : p;
        acc1 += ((k >> 1) & 1) ? -p : p;
        acc2 += ((k >> 0) & 1) ? -p : p;
        acc3 += p * sgn3;
    }
    ((float4*)out)[b] = make_float4(acc0.x + acc0.y, acc1.x + acc1.y,
                                    acc2.x + acc2.y, acc3.x + acc3.y);
}

extern "C" void kernel_launch(void* const* d_in, const int* in_sizes, int n_in,
                              void* d_out, int out_size, void* d_ws, size_t ws_size,
                              hipStream_t stream) {
    const float* inputs = (const float*)d_in[0];   // [B,4] fp32
    const float* rot = (const float*)d_in[1];      // [6,4,3] fp32
    float* out = (float*)d_out;                    // [B,4] fp32
    const int batch = in_sizes[0] / NQ;
    const int grid = (batch + BLOCK - 1) / BLOCK;
    vqc_kernel<<<grid, BLOCK, 0, stream>>>(inputs, rot, out, batch);
}